// Round 2
// baseline (266.022 us; speedup 1.0000x reference)
//
#include <hip/hip_runtime.h>
#include <hip/hip_bf16.h>

typedef unsigned short ushort_t;
typedef __attribute__((ext_vector_type(4))) short bf16x4_t;   // 4 x bf16 (2 VGPRs)
typedef __attribute__((ext_vector_type(8))) short short8;     // 8 x bf16
typedef __attribute__((ext_vector_type(4))) unsigned short ushort4_t;
typedef __attribute__((ext_vector_type(4))) float f32x4;
typedef __attribute__((ext_vector_type(2))) unsigned int uint2_t;
typedef __attribute__((ext_vector_type(4))) unsigned int uint4_t;

#define LOG2E 1.44269504088896340736f

__device__ __forceinline__ unsigned short f2bf(float f) {
    unsigned int u = __float_as_uint(f);
    u += 0x7fffu + ((u >> 16) & 1u);          // round-to-nearest-even
    return (unsigned short)(u >> 16);
}

__device__ __forceinline__ unsigned int pk2bf(float a, float b) {
    union { __hip_bfloat162 h2; unsigned int u; } cvt;
    cvt.h2 = __float22bfloat162_rn(make_float2(a, b));   // v_cvt_pk_bf16_f32
    return cvt.u;
}

__device__ __forceinline__ void gl_lds16(const ushort_t* g, ushort_t* l) {
    __builtin_amdgcn_global_load_lds(
        (const __attribute__((address_space(1))) unsigned int*)g,
        (__attribute__((address_space(3))) unsigned int*)l, 16, 0, 0);
}

// K=16 bf16 MFMA: A/B = 4 bf16 (2 VGPRs). S^T C-frag == PV A-frag for this shape.
__device__ __forceinline__ f32x4 mfma16(uint2_t a, uint2_t b, f32x4 c) {
    union { uint2_t u; bf16x4_t s; } ua, ub;
    ua.u = a; ub.u = b;
    return __builtin_amdgcn_mfma_f32_16x16x16bf16_1k(ua.s, ub.s, c, 0, 0, 0);
}

// ---------------------------------------------------------------------------
// Merged conversion kernel (one launch instead of two):
//  blocks [0, 4096):    x (fp32 [8192][1024]) -> xb (bf16, same layout)
//  blocks [4096, 5632): w (fp32 [1024][3072]) -> wt (bf16 [3072][1024]) transp
// ---------------------------------------------------------------------------
__global__ __launch_bounds__(256) void cvt_xw(
    const float* __restrict__ x, ushort_t* __restrict__ xb,
    const float* __restrict__ w, ushort_t* __restrict__ wt)
{
    __shared__ ushort_t Ts[64][40];           // [n][k] (w path only)
    const int bid = blockIdx.x;
    const int tid = threadIdx.x;
    if (bid < 4096) {
        const size_t i = ((size_t)bid * 256 + tid) * 8;
        const float4 a = *(const float4*)(x + i);
        const float4 b = *(const float4*)(x + i + 4);
        uint4_t o;
        o[0] = pk2bf(a.x, a.y); o[1] = pk2bf(a.z, a.w);
        o[2] = pk2bf(b.x, b.y); o[3] = pk2bf(b.z, b.w);
        *(uint4_t*)(xb + i) = o;
    } else {
        const int wb = bid - 4096;
        const int k0 = (wb & 31) * 32, n0 = (wb >> 5) * 64;
        const int kr = tid >> 3, nc = (tid & 7) * 8;
        const float* g = w + (size_t)(k0 + kr) * 3072 + n0 + nc;
        const float4 a = *(const float4*)g;
        const float4 b = *(const float4*)(g + 4);
        const float vals[8] = {a.x, a.y, a.z, a.w, b.x, b.y, b.z, b.w};
#pragma unroll
        for (int j = 0; j < 8; ++j) Ts[nc + j][kr] = f2bf(vals[j]);
        __syncthreads();
        const int nr = tid >> 2, kc = (tid & 3) * 8;
        const short8 v = *(const short8*)&Ts[nr][kc];
        *(short8*)(wt + (size_t)(n0 + nr) * 1024 + k0 + kc) = v;
    }
}

// ---------------------------------------------------------------------------
// qkv = xb @ wt^T + b.  BM=128, BN=128, BK=32.
// Double-buffered global_load_lds staging, ONE barrier per K-step (T3 min).
// LDS is stored in MFMA-FRAGMENT ORDER (T2 via pre-permuted global source,
// m173 pattern): subtile s = 16 rows x 32 k, stored as 64 lanes x 16B where
// lane l holds (row s*16+(l&15), k (l>>4)*8..+7). global_load_lds writes
// linearly (base + lane*16), fragment ds_read_b128 is base + lane*16 ->
// both staging writes and fragment reads are bank-conflict-free.
// Epilogue: +bias; K,Q -> [bh][t][d]; V -> [bh][d][t].
// ---------------------------------------------------------------------------
__global__ __launch_bounds__(256) void qkv_gemm(
    const ushort_t* __restrict__ xb, const ushort_t* __restrict__ wt,
    const float* __restrict__ bq,
    ushort_t* __restrict__ kws, ushort_t* __restrict__ qws,
    ushort_t* __restrict__ vws)
{
    __shared__ ushort_t As[2][128 * 32];      // [buf][subtile s][lane frag 16B]
    __shared__ ushort_t Bs[2][128 * 32];

    const int tid  = threadIdx.x;
    const int m0   = blockIdx.x * 128;
    const int n0   = blockIdx.y * 128;
    const int wv   = tid >> 6;
    const int lane = tid & 63;
    const int qr   = lane & 15;
    const int quad = lane >> 4;
    const int wm   = (wv >> 1) * 64;
    const int wn   = (wv & 1) * 64;

    // staging source: wave wv owns subtiles {2wv, 2wv+1} of both A and B.
    // lane l stages (row = s*16 + (l&15), k = (l>>4)*8 .. +7).
    const int fr = lane & 15;
    const int fk = (lane >> 4) * 8;
    const ushort_t* gA = xb + (size_t)(m0 + 2*wv*16 + fr) * 1024 + fk;
    const ushort_t* gB = wt + (size_t)(n0 + 2*wv*16 + fr) * 1024 + fk;
    const int sdst = 2 * wv * 512;            // ushort offset of subtile 2wv

    // fragment-read subtile bases for this wave
    const int sa = (wv >> 1) * 4;             // A subtiles sa..sa+3
    const int sb = (wv & 1) * 4;              // B subtiles sb..sb+3

    f32x4 acc[4][4];
#pragma unroll
    for (int i = 0; i < 4; ++i)
#pragma unroll
        for (int j = 0; j < 4; ++j) acc[i][j] = (f32x4){0.f, 0.f, 0.f, 0.f};

    // prologue: stage K-tile 0 into buf 0
    gl_lds16(gA,            As[0] + sdst);
    gl_lds16(gA + 16*1024,  As[0] + sdst + 512);
    gl_lds16(gB,            Bs[0] + sdst);
    gl_lds16(gB + 16*1024,  Bs[0] + sdst + 512);
    __syncthreads();

    for (int kt = 0; kt < 32; ++kt) {
        const int cur = kt & 1;
        if (kt < 31) {                        // issue next tile (stays in flight
            const int k1 = (kt + 1) * 32;     //  across the MFMA block below)
            gl_lds16(gA + k1,           As[cur^1] + sdst);
            gl_lds16(gA + k1 + 16*1024, As[cur^1] + sdst + 512);
            gl_lds16(gB + k1,           Bs[cur^1] + sdst);
            gl_lds16(gB + k1 + 16*1024, Bs[cur^1] + sdst + 512);
        }

        short8 af[4], bfr[4];
#pragma unroll
        for (int i = 0; i < 4; ++i)
            af[i] = *(const short8*)&As[cur][(sa + i) * 512 + lane * 8];
#pragma unroll
        for (int j = 0; j < 4; ++j)
            bfr[j] = *(const short8*)&Bs[cur][(sb + j) * 512 + lane * 8];
#pragma unroll
        for (int i = 0; i < 4; ++i)
#pragma unroll
            for (int j = 0; j < 4; ++j)
                acc[i][j] = __builtin_amdgcn_mfma_f32_16x16x32_bf16(
                    af[i], bfr[j], acc[i][j], 0, 0, 0);

        __syncthreads();                      // drains vmcnt(0): next buf ready,
    }                                         // and all reads of cur are done

    const int nbase = n0 + wn;
    const int sec   = nbase >> 10;            // 0=K, 1=Q, 2=V
    const int h     = (nbase & 1023) >> 6;

    if (sec == 2) {
#pragma unroll
        for (int j = 0; j < 4; ++j) {
            const float bias = bq[nbase + j*16 + qr];
            const int d = j*16 + qr;
#pragma unroll
            for (int i = 0; i < 4; ++i) {
                const int m  = m0 + wm + i*16 + quad*4;
                const int bb = m >> 11;
                const int tt = m & 2047;
                ushort4_t pk;
#pragma unroll
                for (int r = 0; r < 4; ++r) pk[r] = f2bf(acc[i][j][r] + bias);
                *(ushort4_t*)&vws[((size_t)(bb*16 + h)*64 + d)*2048 + tt] = pk;
            }
        }
    } else {
        ushort_t* __restrict__ dst = (sec == 0) ? kws : qws;
#pragma unroll
        for (int j = 0; j < 4; ++j) {
            const float bias = bq[nbase + j*16 + qr];
            const int d = j*16 + qr;
#pragma unroll
            for (int i = 0; i < 4; ++i) {
#pragma unroll
                for (int r = 0; r < 4; ++r) {
                    const int m  = m0 + wm + i*16 + quad*4 + r;
                    const int bb = m >> 11;
                    const int tt = m & 2047;
                    dst[(((size_t)(bb*16 + h)) * 2048 + tt) * 64 + d] =
                        f2bf(acc[i][j][r] + bias);
                }
            }
        }
    }
}

// ---------------------------------------------------------------------------
// Causal flash attention. 512 threads / 8 waves per block; each wave owns 16
// q-rows. Deterministic balanced pairing: block (bh, j) processes q-tiles j
// and 15-j -> exactly 34 k-tile iterations per block. Double-buffered K/V
// staged through registers, constant-max softmax fused per 16-key chunk,
// PV from registers via 16x16x16 MFMA.
// ---------------------------------------------------------------------------
__global__ __launch_bounds__(512) void attn_fwd(
    const ushort_t* __restrict__ kws, const ushort_t* __restrict__ qws,
    const ushort_t* __restrict__ vws, float* __restrict__ out)
{
    constexpr int LDK = 72;                   // 64 + 8 pad (rows 16B-aligned)
    __shared__ ushort_t Ks[2][64 * LDK];      // [buf][key][d]
    __shared__ ushort_t Vs[2][64 * LDK];      // [buf][d][t]

    const int tid  = threadIdx.x;
    const int wv   = tid >> 6;                // 0..7
    const int lane = tid & 63;
    const int qr   = lane & 15;
    const int quad = lane >> 4;
    const int srow = tid >> 3;                // 0..63 (512 thr x 16B = 8KB tile)
    const int scol = (tid & 7) * 8;           // 0..56
    constexpr float SCL = 0.125f * LOG2E;     // 1/sqrt(64), log2 domain
    constexpr float CB  = 8.0f;               // fixed max bound (log2 units)

    const int bh = (int)blockIdx.x >> 3;      // 8 pair-items per bh -> XCD spread
    const int jp = (int)blockIdx.x & 7;
    const size_t bhT = (size_t)bh * 2048;
    const ushort_t* kbase = kws + bhT * 64;
    const ushort_t* vbase = vws + (size_t)bh * 64 * 2048;
    const int b = bh >> 4, h = bh & 15;

#pragma unroll 1
    for (int part = 0; part < 2; ++part) {
        const int qt = part ? (15 - jp) : jp; // pair sums to 34 k-tiles always
        const int q0 = qt * 128;

        const int base = q0 + wv*16;          // this wave's 16 q-rows
        const int qv0 = base + qr;            // softmax-domain q (q = lane&15)

        const ushort_t* qg0 = qws + (bhT + qv0) * 64;
        const short8 Qb00 = *(const short8*)(qg0 + quad*8);
        const short8 Qb01 = *(const short8*)(qg0 + 32 + quad*8);

        float l_s = 0.f;
        f32x4 Oacc[4];
#pragma unroll
        for (int dt = 0; dt < 4; ++dt) Oacc[dt] = (f32x4){0.f,0.f,0.f,0.f};

        const int nkt = 2*qt + 2;
        const int row_max = base + 15;

        // prologue: tile 0 -> regs -> buf0
        short8 kv0, vv0;
        {
            const ushort_t* kg = kbase + (size_t)srow * 64 + scol;
            const ushort_t* vg = vbase + (size_t)srow * 2048 + scol;
            kv0 = *(const short8*)(kg);
            vv0 = *(const short8*)(vg);
        }
        *(short8*)&Ks[0][srow * LDK + scol] = kv0;
        *(short8*)&Vs[0][srow * LDK + scol] = vv0;
        __syncthreads();

        for (int kt = 0; kt < nkt; ++kt) {
            const int k0 = kt * 64;
            const int cur = kt & 1;
            const bool more = (kt + 1 < nkt);
            if (more) {                       // issue next-tile loads (in flight)
                const ushort_t* kg = kbase + (size_t)(k0 + 64 + srow) * 64 + scol;
                const ushort_t* vg = vbase + (size_t)srow * 2048 + k0 + 64 + scol;
                kv0 = *(const short8*)(kg);
                vv0 = *(const short8*)(vg);
            }

            if (k0 <= row_max) {
                const ushort_t* Kc = Ks[cur];
                const ushort_t* Vc = Vs[cur];
                const bool diag = (k0 + 63 > base);   // wave-uniform

                // Per 16-key chunk: S^T = K Q^T, mask, exp2, pack -> pks.
                uint2_t pks[4];
                float ps0 = 0.f;
#pragma unroll
                for (int t4 = 0; t4 < 4; ++t4) {
                    const short8 kf0 = *(const short8*)&Kc[(t4*16 + qr)*LDK + quad*8];
                    const short8 kf1 = *(const short8*)&Kc[(t4*16 + qr)*LDK + 32 + quad*8];
                    f32x4 a = (f32x4){0.f,0.f,0.f,0.f};
                    a = __builtin_amdgcn_mfma_f32_16x16x32_bf16(kf0, Qb00, a, 0,0,0);
                    a = __builtin_amdgcn_mfma_f32_16x16x32_bf16(kf1, Qb01, a, 0,0,0);
                    if (diag) {
#pragma unroll
                        for (int r = 0; r < 4; ++r) {
                            const int key = k0 + t4*16 + quad*4 + r;
                            if (key > qv0) a[r] = -INFINITY;
                        }
                    }
                    float p0[4];
#pragma unroll
                    for (int r = 0; r < 4; ++r) {
                        p0[r] = exp2f(__builtin_fmaf(a[r], SCL, -CB));
                        ps0 += p0[r];
                    }
                    pks[t4][0] = pk2bf(p0[0], p0[1]);
                    pks[t4][1] = pk2bf(p0[2], p0[3]);
                }
                l_s += ps0;

                // O += P V : B-frag = V[key][d] from Vs[d][t], k=quad*4..+3
                __builtin_amdgcn_s_setprio(1);
#pragma unroll
                for (int dt = 0; dt < 4; ++dt) {
#pragma unroll
                    for (int t4 = 0; t4 < 4; ++t4) {
                        const uint2_t vf = *(const uint2_t*)
                            &Vc[(dt*16 + qr)*LDK + t4*16 + quad*4];
                        Oacc[dt] = mfma16(pks[t4], vf, Oacc[dt]);
                    }
                }
                __builtin_amdgcn_s_setprio(0);
            }

            if (more) {                       // stage tile kt+1 into other buf
                *(short8*)&Ks[cur ^ 1][srow * LDK + scol] = kv0;
                *(short8*)&Vs[cur ^ 1][srow * LDK + scol] = vv0;
            }
            __syncthreads();                  // buf ready / reads of cur done
        }

        // epilogue: reduce l across quads, store
        float lf = l_s;
        lf += __shfl_xor(lf, 16);
        lf += __shfl_xor(lf, 32);
#pragma unroll
        for (int r = 0; r < 4; ++r) {
            const float lr  = __shfl(lf, quad*4 + r);
            const float inv = 1.f / lr;
            const int q = q0 + wv*16 + quad*4 + r;
            float* o = out + ((size_t)(b*2048 + q)) * 1024 + h*64;
#pragma unroll
            for (int dt = 0; dt < 4; ++dt) o[dt*16 + qr] = Oacc[dt][r] * inv;
        }
    }
}

extern "C" void kernel_launch(void* const* d_in, const int* in_sizes, int n_in,
                              void* d_out, int out_size, void* d_ws, size_t ws_size,
                              hipStream_t stream) {
    (void)in_sizes; (void)n_in; (void)out_size; (void)ws_size;
    const float* x  = (const float*)d_in[0];
    const float* w  = (const float*)d_in[1];
    const float* bq = (const float*)d_in[2];
    float* out = (float*)d_out;

    ushort_t* kws = (ushort_t*)d_ws;
    ushort_t* qws = kws + (size_t)8388608;
    ushort_t* vws = qws + (size_t)8388608;
    ushort_t* xb  = vws + (size_t)8388608;
    ushort_t* wt  = xb  + (size_t)8388608;

    cvt_xw<<<5632, 256, 0, stream>>>(x, xb, w, wt);
    qkv_gemm<<<dim3(64, 24), 256, 0, stream>>>(xb, wt, bq, kws, qws, vws);
    attn_fwd<<<512, 512, 0, stream>>>(kws, qws, vws, out);
}

// Round 3
// 222.659 us; speedup vs baseline: 1.1947x; 1.1947x over previous
//
#include <hip/hip_runtime.h>
#include <hip/hip_bf16.h>

typedef unsigned short ushort_t;
typedef __attribute__((ext_vector_type(4))) short bf16x4_t;   // 4 x bf16 (2 VGPRs)
typedef __attribute__((ext_vector_type(8))) short short8;     // 8 x bf16
typedef __attribute__((ext_vector_type(4))) unsigned short ushort4_t;
typedef __attribute__((ext_vector_type(4))) float f32x4;
typedef __attribute__((ext_vector_type(2))) unsigned int uint2_t;
typedef __attribute__((ext_vector_type(4))) unsigned int uint4_t;

#define LOG2E 1.44269504088896340736f

__device__ __forceinline__ unsigned short f2bf(float f) {
    unsigned int u = __float_as_uint(f);
    u += 0x7fffu + ((u >> 16) & 1u);          // round-to-nearest-even
    return (unsigned short)(u >> 16);
}

__device__ __forceinline__ unsigned int pk2bf(float a, float b) {
    union { __hip_bfloat162 h2; unsigned int u; } cvt;
    cvt.h2 = __float22bfloat162_rn(make_float2(a, b));   // v_cvt_pk_bf16_f32
    return cvt.u;
}

__device__ __forceinline__ void gl_lds16(const ushort_t* g, ushort_t* l) {
    __builtin_amdgcn_global_load_lds(
        (const __attribute__((address_space(1))) unsigned int*)g,
        (__attribute__((address_space(3))) unsigned int*)l, 16, 0, 0);
}

// K=16 bf16 MFMA: A/B = 4 bf16 (2 VGPRs). S^T C-frag == PV A-frag for this shape.
__device__ __forceinline__ f32x4 mfma16(uint2_t a, uint2_t b, f32x4 c) {
    union { uint2_t u; bf16x4_t s; } ua, ub;
    ua.u = a; ub.u = b;
    return __builtin_amdgcn_mfma_f32_16x16x16bf16_1k(ua.s, ub.s, c, 0, 0, 0);
}

// ---------------------------------------------------------------------------
// Merged conversion kernel (one launch instead of two):
//  blocks [0, 4096):    x (fp32 [8192][1024]) -> xb (bf16, same layout)
//  blocks [4096, 5632): w (fp32 [1024][3072]) -> wt (bf16 [3072][1024]) transp
// ---------------------------------------------------------------------------
__global__ __launch_bounds__(256) void cvt_xw(
    const float* __restrict__ x, ushort_t* __restrict__ xb,
    const float* __restrict__ w, ushort_t* __restrict__ wt)
{
    __shared__ ushort_t Ts[64][40];           // [n][k] (w path only)
    const int bid = blockIdx.x;
    const int tid = threadIdx.x;
    if (bid < 4096) {
        const size_t i = ((size_t)bid * 256 + tid) * 8;
        const float4 a = *(const float4*)(x + i);
        const float4 b = *(const float4*)(x + i + 4);
        uint4_t o;
        o[0] = pk2bf(a.x, a.y); o[1] = pk2bf(a.z, a.w);
        o[2] = pk2bf(b.x, b.y); o[3] = pk2bf(b.z, b.w);
        *(uint4_t*)(xb + i) = o;
    } else {
        const int wb = bid - 4096;
        const int k0 = (wb & 31) * 32, n0 = (wb >> 5) * 64;
        const int kr = tid >> 3, nc = (tid & 7) * 8;
        const float* g = w + (size_t)(k0 + kr) * 3072 + n0 + nc;
        const float4 a = *(const float4*)g;
        const float4 b = *(const float4*)(g + 4);
        const float vals[8] = {a.x, a.y, a.z, a.w, b.x, b.y, b.z, b.w};
#pragma unroll
        for (int j = 0; j < 8; ++j) Ts[nc + j][kr] = f2bf(vals[j]);
        __syncthreads();
        const int nr = tid >> 2, kc = (tid & 3) * 8;
        const short8 v = *(const short8*)&Ts[nr][kc];
        *(short8*)(wt + (size_t)(n0 + nr) * 1024 + k0 + kc) = v;
    }
}

// ---------------------------------------------------------------------------
// qkv = xb @ wt^T + b.  BM=128, BN=128, BK=32.
// T3+T4 pipeline: 3 LDS buffers, prefetch distance 2, raw s_barrier with
// counted `s_waitcnt vmcnt(4)` (never 0 in main loop) -> loads stay in
// flight across barriers; ONE barrier per K-step; lgkmcnt(0) fence at step
// end covers the WAR on buffer reuse.
// Staging is lane-contiguous in global (4 lanes = one 64B line, permuted
// within the line); LDS slot (R,c16B) holds data (R, c ^ ((R>>1)&3)) ->
// fragment ds_read_b128 at R*64B + (quad^((qr>>1)&3))*16B spreads 16 lanes
// over all 8 bank slots = conflict-free (2-way). Read mapping == round-1 data.
// Epilogue: +bias; K,Q -> [bh][t][d]; V -> [bh][d][t].
// ---------------------------------------------------------------------------
__global__ __launch_bounds__(256) void qkv_gemm(
    const ushort_t* __restrict__ xb, const ushort_t* __restrict__ wt,
    const float* __restrict__ bq,
    ushort_t* __restrict__ kws, ushort_t* __restrict__ qws,
    ushort_t* __restrict__ vws)
{
    __shared__ ushort_t As[3][128 * 32];      // [buf][row][k] (k XOR-swizzled)
    __shared__ ushort_t Bs[3][128 * 32];

    const int tid  = threadIdx.x;
    const int m0   = blockIdx.x * 128;
    const int n0   = blockIdx.y * 128;
    const int wv   = tid >> 6;
    const int lane = tid & 63;
    const int qr   = lane & 15;
    const int quad = lane >> 4;
    const int wm   = (wv >> 1) * 64;
    const int wn   = (wv & 1) * 64;

    // staging: lane l covers (row = wv*32 [+16] + (l>>2), kchunk = l&3),
    // fetching the chunk that belongs at its linear LDS slot under the
    // swizzle: global chunk = (l&3) ^ ((lr>>1)&3). Same 64B line per quad.
    const int lr   = lane >> 2;               // 0..15
    const int csw  = (lane & 3) ^ ((lr >> 1) & 3);
    const ushort_t* gA = xb + (size_t)(m0 + wv*32 + lr) * 1024 + csw*8;
    const ushort_t* gB = wt + (size_t)(n0 + wv*32 + lr) * 1024 + csw*8;
    const int sdst = wv * 1024;               // ushort offset within a buffer

    // fragment read: per-thread constant swizzled 16B chunk index
    const int swq = quad ^ ((qr >> 1) & 3);

    f32x4 acc[4][4];
#pragma unroll
    for (int i = 0; i < 4; ++i)
#pragma unroll
        for (int j = 0; j < 4; ++j) acc[i][j] = (f32x4){0.f, 0.f, 0.f, 0.f};

    // prologue: stage tiles 0 and 1 into bufs 0 and 1 (8 loads in flight)
    gl_lds16(gA,             (ushort_t*)As + sdst);
    gl_lds16(gA + 16*1024,   (ushort_t*)As + sdst + 512);
    gl_lds16(gB,             (ushort_t*)Bs + sdst);
    gl_lds16(gB + 16*1024,   (ushort_t*)Bs + sdst + 512);
    gl_lds16(gA + 32,            (ushort_t*)As + 4096 + sdst);
    gl_lds16(gA + 32 + 16*1024,  (ushort_t*)As + 4096 + sdst + 512);
    gl_lds16(gB + 32,            (ushort_t*)Bs + 4096 + sdst);
    gl_lds16(gB + 32 + 16*1024,  (ushort_t*)Bs + 4096 + sdst + 512);

    int bufc = 0;                             // kt % 3
    for (int kt = 0; kt < 32; ++kt) {
        // tile kt (oldest 4 own loads) must be complete; tile kt+1 stays in
        // flight across the barrier (T4). Last tile: full drain.
        if (kt < 31) asm volatile("s_waitcnt vmcnt(4)" ::: "memory");
        else         asm volatile("s_waitcnt vmcnt(0)" ::: "memory");
        __builtin_amdgcn_s_barrier();         // buf[kt%3] ready for everyone
        __builtin_amdgcn_sched_barrier(0);

        const ushort_t* cA = (const ushort_t*)As + bufc * 4096;
        const ushort_t* cB = (const ushort_t*)Bs + bufc * 4096;
        short8 af[4], bfr[4];
#pragma unroll
        for (int i = 0; i < 4; ++i)
            af[i] = *(const short8*)&cA[(wm + i*16 + qr) * 32 + swq * 8];
#pragma unroll
        for (int j = 0; j < 4; ++j)
            bfr[j] = *(const short8*)&cB[(wn + j*16 + qr) * 32 + swq * 8];

        if (kt < 30) {                        // stage tile kt+2 (after barrier:
            int b2 = bufc + 2;                //  all waves done reading buf b2)
            if (b2 >= 3) b2 -= 3;
            const int k2 = (kt + 2) * 32;
            ushort_t* dA = (ushort_t*)As + b2 * 4096 + sdst;
            ushort_t* dB = (ushort_t*)Bs + b2 * 4096 + sdst;
            gl_lds16(gA + k2,            dA);
            gl_lds16(gA + k2 + 16*1024,  dA + 512);
            gl_lds16(gB + k2,            dB);
            gl_lds16(gB + k2 + 16*1024,  dB + 512);
        }

#pragma unroll
        for (int i = 0; i < 4; ++i)
#pragma unroll
            for (int j = 0; j < 4; ++j)
                acc[i][j] = __builtin_amdgcn_mfma_f32_16x16x32_bf16(
                    af[i], bfr[j], acc[i][j], 0, 0, 0);

        // all my ds_reads of buf[kt%3] serviced before next barrier releases
        // writers into it (WAR). Near-free: MFMAs already consumed them.
        asm volatile("s_waitcnt lgkmcnt(0)" ::: "memory");
        bufc = (bufc == 2) ? 0 : bufc + 1;
    }

    const int nbase = n0 + wn;
    const int sec   = nbase >> 10;            // 0=K, 1=Q, 2=V
    const int h     = (nbase & 1023) >> 6;

    if (sec == 2) {
#pragma unroll
        for (int j = 0; j < 4; ++j) {
            const float bias = bq[nbase + j*16 + qr];
            const int d = j*16 + qr;
#pragma unroll
            for (int i = 0; i < 4; ++i) {
                const int m  = m0 + wm + i*16 + quad*4;
                const int bb = m >> 11;
                const int tt = m & 2047;
                ushort4_t pk;
#pragma unroll
                for (int r = 0; r < 4; ++r) pk[r] = f2bf(acc[i][j][r] + bias);
                *(ushort4_t*)&vws[((size_t)(bb*16 + h)*64 + d)*2048 + tt] = pk;
            }
        }
    } else {
        ushort_t* __restrict__ dst = (sec == 0) ? kws : qws;
#pragma unroll
        for (int j = 0; j < 4; ++j) {
            const float bias = bq[nbase + j*16 + qr];
            const int d = j*16 + qr;
#pragma unroll
            for (int i = 0; i < 4; ++i) {
#pragma unroll
                for (int r = 0; r < 4; ++r) {
                    const int m  = m0 + wm + i*16 + quad*4 + r;
                    const int bb = m >> 11;
                    const int tt = m & 2047;
                    dst[(((size_t)(bb*16 + h)) * 2048 + tt) * 64 + d] =
                        f2bf(acc[i][j][r] + bias);
                }
            }
        }
    }
}

// ---------------------------------------------------------------------------
// Causal flash attention. 512 threads / 8 waves per block; each wave owns 16
// q-rows. Deterministic balanced pairing: block (bh, j) processes q-tiles j
// and 15-j -> exactly 34 k-tile iterations per block. Double-buffered K/V
// staged through registers, constant-max softmax fused per 16-key chunk,
// PV from registers via 16x16x16 MFMA.
// ---------------------------------------------------------------------------
__global__ __launch_bounds__(512) void attn_fwd(
    const ushort_t* __restrict__ kws, const ushort_t* __restrict__ qws,
    const ushort_t* __restrict__ vws, float* __restrict__ out)
{
    constexpr int LDK = 72;                   // 64 + 8 pad (rows 16B-aligned)
    __shared__ ushort_t Ks[2][64 * LDK];      // [buf][key][d]
    __shared__ ushort_t Vs[2][64 * LDK];      // [buf][d][t]

    const int tid  = threadIdx.x;
    const int wv   = tid >> 6;                // 0..7
    const int lane = tid & 63;
    const int qr   = lane & 15;
    const int quad = lane >> 4;
    const int srow = tid >> 3;                // 0..63 (512 thr x 16B = 8KB tile)
    const int scol = (tid & 7) * 8;           // 0..56
    constexpr float SCL = 0.125f * LOG2E;     // 1/sqrt(64), log2 domain
    constexpr float CB  = 8.0f;               // fixed max bound (log2 units)

    const int bh = (int)blockIdx.x >> 3;      // 8 pair-items per bh -> XCD spread
    const int jp = (int)blockIdx.x & 7;
    const size_t bhT = (size_t)bh * 2048;
    const ushort_t* kbase = kws + bhT * 64;
    const ushort_t* vbase = vws + (size_t)bh * 64 * 2048;
    const int b = bh >> 4, h = bh & 15;

#pragma unroll 1
    for (int part = 0; part < 2; ++part) {
        const int qt = part ? (15 - jp) : jp; // pair sums to 34 k-tiles always
        const int q0 = qt * 128;

        const int base = q0 + wv*16;          // this wave's 16 q-rows
        const int qv0 = base + qr;            // softmax-domain q (q = lane&15)

        const ushort_t* qg0 = qws + (bhT + qv0) * 64;
        const short8 Qb00 = *(const short8*)(qg0 + quad*8);
        const short8 Qb01 = *(const short8*)(qg0 + 32 + quad*8);

        float l_s = 0.f;
        f32x4 Oacc[4];
#pragma unroll
        for (int dt = 0; dt < 4; ++dt) Oacc[dt] = (f32x4){0.f,0.f,0.f,0.f};

        const int nkt = 2*qt + 2;
        const int row_max = base + 15;

        // prologue: tile 0 -> regs -> buf0
        short8 kv0, vv0;
        {
            const ushort_t* kg = kbase + (size_t)srow * 64 + scol;
            const ushort_t* vg = vbase + (size_t)srow * 2048 + scol;
            kv0 = *(const short8*)(kg);
            vv0 = *(const short8*)(vg);
        }
        *(short8*)&Ks[0][srow * LDK + scol] = kv0;
        *(short8*)&Vs[0][srow * LDK + scol] = vv0;
        __syncthreads();

        for (int kt = 0; kt < nkt; ++kt) {
            const int k0 = kt * 64;
            const int cur = kt & 1;
            const bool more = (kt + 1 < nkt);
            if (more) {                       // issue next-tile loads (in flight)
                const ushort_t* kg = kbase + (size_t)(k0 + 64 + srow) * 64 + scol;
                const ushort_t* vg = vbase + (size_t)srow * 2048 + k0 + 64 + scol;
                kv0 = *(const short8*)(kg);
                vv0 = *(const short8*)(vg);
            }

            if (k0 <= row_max) {
                const ushort_t* Kc = Ks[cur];
                const ushort_t* Vc = Vs[cur];
                const bool diag = (k0 + 63 > base);   // wave-uniform

                // Per 16-key chunk: S^T = K Q^T, mask, exp2, pack -> pks.
                uint2_t pks[4];
                float ps0 = 0.f;
#pragma unroll
                for (int t4 = 0; t4 < 4; ++t4) {
                    const short8 kf0 = *(const short8*)&Kc[(t4*16 + qr)*LDK + quad*8];
                    const short8 kf1 = *(const short8*)&Kc[(t4*16 + qr)*LDK + 32 + quad*8];
                    f32x4 a = (f32x4){0.f,0.f,0.f,0.f};
                    a = __builtin_amdgcn_mfma_f32_16x16x32_bf16(kf0, Qb00, a, 0,0,0);
                    a = __builtin_amdgcn_mfma_f32_16x16x32_bf16(kf1, Qb01, a, 0,0,0);
                    if (diag) {
#pragma unroll
                        for (int r = 0; r < 4; ++r) {
                            const int key = k0 + t4*16 + quad*4 + r;
                            if (key > qv0) a[r] = -INFINITY;
                        }
                    }
                    float p0[4];
#pragma unroll
                    for (int r = 0; r < 4; ++r) {
                        p0[r] = exp2f(__builtin_fmaf(a[r], SCL, -CB));
                        ps0 += p0[r];
                    }
                    pks[t4][0] = pk2bf(p0[0], p0[1]);
                    pks[t4][1] = pk2bf(p0[2], p0[3]);
                }
                l_s += ps0;

                // O += P V : B-frag = V[key][d] from Vs[d][t], k=quad*4..+3
                __builtin_amdgcn_s_setprio(1);
#pragma unroll
                for (int dt = 0; dt < 4; ++dt) {
#pragma unroll
                    for (int t4 = 0; t4 < 4; ++t4) {
                        const uint2_t vf = *(const uint2_t*)
                            &Vc[(dt*16 + qr)*LDK + t4*16 + quad*4];
                        Oacc[dt] = mfma16(pks[t4], vf, Oacc[dt]);
                    }
                }
                __builtin_amdgcn_s_setprio(0);
            }

            if (more) {                       // stage tile kt+1 into other buf
                *(short8*)&Ks[cur ^ 1][srow * LDK + scol] = kv0;
                *(short8*)&Vs[cur ^ 1][srow * LDK + scol] = vv0;
            }
            __syncthreads();                  // buf ready / reads of cur done
        }

        // epilogue: reduce l across quads, store
        float lf = l_s;
        lf += __shfl_xor(lf, 16);
        lf += __shfl_xor(lf, 32);
#pragma unroll
        for (int r = 0; r < 4; ++r) {
            const float lr  = __shfl(lf, quad*4 + r);
            const float inv = 1.f / lr;
            const int q = q0 + wv*16 + quad*4 + r;
            float* o = out + ((size_t)(b*2048 + q)) * 1024 + h*64;
#pragma unroll
            for (int dt = 0; dt < 4; ++dt) o[dt*16 + qr] = Oacc[dt][r] * inv;
        }
    }
}

extern "C" void kernel_launch(void* const* d_in, const int* in_sizes, int n_in,
                              void* d_out, int out_size, void* d_ws, size_t ws_size,
                              hipStream_t stream) {
    (void)in_sizes; (void)n_in; (void)out_size; (void)ws_size;
    const float* x  = (const float*)d_in[0];
    const float* w  = (const float*)d_in[1];
    const float* bq = (const float*)d_in[2];
    float* out = (float*)d_out;

    ushort_t* kws = (ushort_t*)d_ws;
    ushort_t* qws = kws + (size_t)8388608;
    ushort_t* vws = qws + (size_t)8388608;
    ushort_t* xb  = vws + (size_t)8388608;
    ushort_t* wt  = xb  + (size_t)8388608;

    cvt_xw<<<5632, 256, 0, stream>>>(x, xb, w, wt);
    qkv_gemm<<<dim3(64, 24), 256, 0, stream>>>(xb, wt, bq, kws, qws, vws);
    attn_fwd<<<512, 512, 0, stream>>>(kws, qws, vws, out);
}

// Round 4
// 216.343 us; speedup vs baseline: 1.2296x; 1.0292x over previous
//
#include <hip/hip_runtime.h>
#include <hip/hip_bf16.h>

typedef unsigned short ushort_t;
typedef __attribute__((ext_vector_type(4))) short bf16x4_t;   // 4 x bf16 (2 VGPRs)
typedef __attribute__((ext_vector_type(8))) short short8;     // 8 x bf16
typedef __attribute__((ext_vector_type(4))) unsigned short ushort4_t;
typedef __attribute__((ext_vector_type(4))) float f32x4;
typedef __attribute__((ext_vector_type(2))) unsigned int uint2_t;
typedef __attribute__((ext_vector_type(4))) unsigned int uint4_t;

#define LOG2E 1.44269504088896340736f

__device__ __forceinline__ unsigned short f2bf(float f) {
    unsigned int u = __float_as_uint(f);
    u += 0x7fffu + ((u >> 16) & 1u);          // round-to-nearest-even
    return (unsigned short)(u >> 16);
}

__device__ __forceinline__ unsigned int pk2bf(float a, float b) {
    union { __hip_bfloat162 h2; unsigned int u; } cvt;
    cvt.h2 = __float22bfloat162_rn(make_float2(a, b));   // v_cvt_pk_bf16_f32
    return cvt.u;
}

__device__ __forceinline__ void gl_lds16(const ushort_t* g, ushort_t* l) {
    __builtin_amdgcn_global_load_lds(
        (const __attribute__((address_space(1))) unsigned int*)g,
        (__attribute__((address_space(3))) unsigned int*)l, 16, 0, 0);
}

// K=16 bf16 MFMA: A/B = 4 bf16 (2 VGPRs). S^T C-frag == PV A-frag for this shape.
__device__ __forceinline__ f32x4 mfma16(uint2_t a, uint2_t b, f32x4 c) {
    union { uint2_t u; bf16x4_t s; } ua, ub;
    ua.u = a; ub.u = b;
    return __builtin_amdgcn_mfma_f32_16x16x16bf16_1k(ua.s, ub.s, c, 0, 0, 0);
}

// ---------------------------------------------------------------------------
// Merged conversion kernel (one launch instead of two):
//  blocks [0, 4096):    x (fp32 [8192][1024]) -> xb (bf16, same layout)
//  blocks [4096, 5632): w (fp32 [1024][3072]) -> wt (bf16 [3072][1024]) transp
// ---------------------------------------------------------------------------
__global__ __launch_bounds__(256) void cvt_xw(
    const float* __restrict__ x, ushort_t* __restrict__ xb,
    const float* __restrict__ w, ushort_t* __restrict__ wt)
{
    __shared__ ushort_t Ts[64][40];           // [n][k] (w path only)
    const int bid = blockIdx.x;
    const int tid = threadIdx.x;
    if (bid < 4096) {
        const size_t i = ((size_t)bid * 256 + tid) * 8;
        const float4 a = *(const float4*)(x + i);
        const float4 b = *(const float4*)(x + i + 4);
        uint4_t o;
        o[0] = pk2bf(a.x, a.y); o[1] = pk2bf(a.z, a.w);
        o[2] = pk2bf(b.x, b.y); o[3] = pk2bf(b.z, b.w);
        *(uint4_t*)(xb + i) = o;
    } else {
        const int wb = bid - 4096;
        const int k0 = (wb & 31) * 32, n0 = (wb >> 5) * 64;
        const int kr = tid >> 3, nc = (tid & 7) * 8;
        const float* g = w + (size_t)(k0 + kr) * 3072 + n0 + nc;
        const float4 a = *(const float4*)g;
        const float4 b = *(const float4*)(g + 4);
        const float vals[8] = {a.x, a.y, a.z, a.w, b.x, b.y, b.z, b.w};
#pragma unroll
        for (int j = 0; j < 8; ++j) Ts[nc + j][kr] = f2bf(vals[j]);
        __syncthreads();
        const int nr = tid >> 2, kc = (tid & 3) * 8;
        const short8 v = *(const short8*)&Ts[nr][kc];
        *(short8*)(wt + (size_t)(n0 + nr) * 1024 + k0 + kc) = v;
    }
}

// ---------------------------------------------------------------------------
// qkv = xb @ wt^T + b.  BM=128, BN=128, BK=32.
// T3+T4 pipeline: 3 LDS buffers, prefetch distance 2, raw s_barrier with
// counted `s_waitcnt vmcnt(4)` (never 0 in main loop) -> loads stay in
// flight across barriers; ONE barrier per K-step; lgkmcnt(0) fence at step
// end covers the WAR on buffer reuse.
// Staging is lane-contiguous in global (4 lanes = one 64B line, permuted
// within the line); LDS slot (R,c16B) holds data (R, c ^ ((R>>1)&3)) ->
// fragment ds_read_b128 at R*64B + (quad^((qr>>1)&3))*16B spreads 16 lanes
// over all 8 bank slots = conflict-free (2-way). Read mapping == round-1 data.
// Epilogue: +bias; K,Q -> [bh][t][d]; V -> [bh][d][t].
// ---------------------------------------------------------------------------
__global__ __launch_bounds__(256) void qkv_gemm(
    const ushort_t* __restrict__ xb, const ushort_t* __restrict__ wt,
    const float* __restrict__ bq,
    ushort_t* __restrict__ kws, ushort_t* __restrict__ qws,
    ushort_t* __restrict__ vws)
{
    __shared__ ushort_t As[3][128 * 32];      // [buf][row][k] (k XOR-swizzled)
    __shared__ ushort_t Bs[3][128 * 32];

    const int tid  = threadIdx.x;
    const int m0   = blockIdx.x * 128;
    const int n0   = blockIdx.y * 128;
    const int wv   = tid >> 6;
    const int lane = tid & 63;
    const int qr   = lane & 15;
    const int quad = lane >> 4;
    const int wm   = (wv >> 1) * 64;
    const int wn   = (wv & 1) * 64;

    // staging: lane l covers (row = wv*32 [+16] + (l>>2), kchunk = l&3),
    // fetching the chunk that belongs at its linear LDS slot under the
    // swizzle: global chunk = (l&3) ^ ((lr>>1)&3). Same 64B line per quad.
    const int lr   = lane >> 2;               // 0..15
    const int csw  = (lane & 3) ^ ((lr >> 1) & 3);
    const ushort_t* gA = xb + (size_t)(m0 + wv*32 + lr) * 1024 + csw*8;
    const ushort_t* gB = wt + (size_t)(n0 + wv*32 + lr) * 1024 + csw*8;
    const int sdst = wv * 1024;               // ushort offset within a buffer

    // fragment read: per-thread constant swizzled 16B chunk index
    const int swq = quad ^ ((qr >> 1) & 3);

    f32x4 acc[4][4];
#pragma unroll
    for (int i = 0; i < 4; ++i)
#pragma unroll
        for (int j = 0; j < 4; ++j) acc[i][j] = (f32x4){0.f, 0.f, 0.f, 0.f};

    // prologue: stage tiles 0 and 1 into bufs 0 and 1 (8 loads in flight)
    gl_lds16(gA,             (ushort_t*)As + sdst);
    gl_lds16(gA + 16*1024,   (ushort_t*)As + sdst + 512);
    gl_lds16(gB,             (ushort_t*)Bs + sdst);
    gl_lds16(gB + 16*1024,   (ushort_t*)Bs + sdst + 512);
    gl_lds16(gA + 32,            (ushort_t*)As + 4096 + sdst);
    gl_lds16(gA + 32 + 16*1024,  (ushort_t*)As + 4096 + sdst + 512);
    gl_lds16(gB + 32,            (ushort_t*)Bs + 4096 + sdst);
    gl_lds16(gB + 32 + 16*1024,  (ushort_t*)Bs + 4096 + sdst + 512);

    int bufc = 0;                             // kt % 3
    for (int kt = 0; kt < 32; ++kt) {
        // tile kt (oldest 4 own loads) must be complete; tile kt+1 stays in
        // flight across the barrier (T4). Last tile: full drain.
        if (kt < 31) asm volatile("s_waitcnt vmcnt(4)" ::: "memory");
        else         asm volatile("s_waitcnt vmcnt(0)" ::: "memory");
        __builtin_amdgcn_s_barrier();         // buf[kt%3] ready for everyone
        __builtin_amdgcn_sched_barrier(0);

        const ushort_t* cA = (const ushort_t*)As + bufc * 4096;
        const ushort_t* cB = (const ushort_t*)Bs + bufc * 4096;
        short8 af[4], bfr[4];
#pragma unroll
        for (int i = 0; i < 4; ++i)
            af[i] = *(const short8*)&cA[(wm + i*16 + qr) * 32 + swq * 8];
#pragma unroll
        for (int j = 0; j < 4; ++j)
            bfr[j] = *(const short8*)&cB[(wn + j*16 + qr) * 32 + swq * 8];

        if (kt < 30) {                        // stage tile kt+2 (after barrier:
            int b2 = bufc + 2;                //  all waves done reading buf b2)
            if (b2 >= 3) b2 -= 3;
            const int k2 = (kt + 2) * 32;
            ushort_t* dA = (ushort_t*)As + b2 * 4096 + sdst;
            ushort_t* dB = (ushort_t*)Bs + b2 * 4096 + sdst;
            gl_lds16(gA + k2,            dA);
            gl_lds16(gA + k2 + 16*1024,  dA + 512);
            gl_lds16(gB + k2,            dB);
            gl_lds16(gB + k2 + 16*1024,  dB + 512);
        }

#pragma unroll
        for (int i = 0; i < 4; ++i)
#pragma unroll
            for (int j = 0; j < 4; ++j)
                acc[i][j] = __builtin_amdgcn_mfma_f32_16x16x32_bf16(
                    af[i], bfr[j], acc[i][j], 0, 0, 0);

        // all my ds_reads of buf[kt%3] serviced before next barrier releases
        // writers into it (WAR). Near-free: MFMAs already consumed them.
        asm volatile("s_waitcnt lgkmcnt(0)" ::: "memory");
        bufc = (bufc == 2) ? 0 : bufc + 1;
    }

    const int nbase = n0 + wn;
    const int sec   = nbase >> 10;            // 0=K, 1=Q, 2=V
    const int h     = (nbase & 1023) >> 6;

    if (sec == 2) {
#pragma unroll
        for (int j = 0; j < 4; ++j) {
            const float bias = bq[nbase + j*16 + qr];
            const int d = j*16 + qr;
#pragma unroll
            for (int i = 0; i < 4; ++i) {
                const int m  = m0 + wm + i*16 + quad*4;
                const int bb = m >> 11;
                const int tt = m & 2047;
                ushort4_t pk;
#pragma unroll
                for (int r = 0; r < 4; ++r) pk[r] = f2bf(acc[i][j][r] + bias);
                *(ushort4_t*)&vws[((size_t)(bb*16 + h)*64 + d)*2048 + tt] = pk;
            }
        }
    } else {
        ushort_t* __restrict__ dst = (sec == 0) ? kws : qws;
#pragma unroll
        for (int j = 0; j < 4; ++j) {
            const float bias = bq[nbase + j*16 + qr];
            const int d = j*16 + qr;
#pragma unroll
            for (int i = 0; i < 4; ++i) {
#pragma unroll
                for (int r = 0; r < 4; ++r) {
                    const int m  = m0 + wm + i*16 + quad*4 + r;
                    const int bb = m >> 11;
                    const int tt = m & 2047;
                    dst[(((size_t)(bb*16 + h)) * 2048 + tt) * 64 + d] =
                        f2bf(acc[i][j][r] + bias);
                }
            }
        }
    }
}

// ---------------------------------------------------------------------------
// Causal flash attention. 512 threads / 8 waves per block; each wave owns 16
// q-rows. ONE q-tile per block (no pairing): grid = 16 qt x 64 bh = 1024
// blocks -> 4 blocks/CU co-resident (36KB LDS x 4 = 147KB), 32 waves/CU,
// vs 2 blocks/CU with pairing. Load imbalance handled by LPT dispatch
// order: qt = 15 - bid/64 launches the 32-iter blocks first. Bonus:
// bid mod 8 == bh mod 8, so all 16 blocks of one head share an XCD's L2
// for K/V. Double-buffered K/V staged through registers, constant-max
// softmax fused per 16-key chunk, PV from registers via 16x16x16 MFMA.
// ---------------------------------------------------------------------------
__global__ __launch_bounds__(512) void attn_fwd(
    const ushort_t* __restrict__ kws, const ushort_t* __restrict__ qws,
    const ushort_t* __restrict__ vws, float* __restrict__ out)
{
    constexpr int LDK = 72;                   // 64 + 8 pad (rows 16B-aligned)
    __shared__ ushort_t Ks[2][64 * LDK];      // [buf][key][d]
    __shared__ ushort_t Vs[2][64 * LDK];      // [buf][d][t]

    const int tid  = threadIdx.x;
    const int wv   = tid >> 6;                // 0..7
    const int lane = tid & 63;
    const int qr   = lane & 15;
    const int quad = lane >> 4;
    const int srow = tid >> 3;                // 0..63 (512 thr x 16B = 8KB tile)
    const int scol = (tid & 7) * 8;           // 0..56
    constexpr float SCL = 0.125f * LOG2E;     // 1/sqrt(64), log2 domain
    constexpr float CB  = 8.0f;               // fixed max bound (log2 units)

    const int bid = (int)blockIdx.x;
    const int qt  = 15 - (bid >> 6);          // LPT: longest blocks first
    const int bh  = bid & 63;
    const size_t bhT = (size_t)bh * 2048;
    const ushort_t* kbase = kws + bhT * 64;
    const ushort_t* vbase = vws + (size_t)bh * 64 * 2048;
    const int b = bh >> 4, h = bh & 15;

    const int q0 = qt * 128;
    const int base = q0 + wv*16;              // this wave's 16 q-rows
    const int qv0 = base + qr;                // softmax-domain q (q = lane&15)

    const ushort_t* qg0 = qws + (bhT + qv0) * 64;
    const short8 Qb00 = *(const short8*)(qg0 + quad*8);
    const short8 Qb01 = *(const short8*)(qg0 + 32 + quad*8);

    float l_s = 0.f;
    f32x4 Oacc[4];
#pragma unroll
    for (int dt = 0; dt < 4; ++dt) Oacc[dt] = (f32x4){0.f,0.f,0.f,0.f};

    const int nkt = 2*qt + 2;
    const int row_max = base + 15;

    // prologue: tile 0 -> regs -> buf0
    short8 kv0, vv0;
    {
        const ushort_t* kg = kbase + (size_t)srow * 64 + scol;
        const ushort_t* vg = vbase + (size_t)srow * 2048 + scol;
        kv0 = *(const short8*)(kg);
        vv0 = *(const short8*)(vg);
    }
    *(short8*)&Ks[0][srow * LDK + scol] = kv0;
    *(short8*)&Vs[0][srow * LDK + scol] = vv0;
    __syncthreads();

    for (int kt = 0; kt < nkt; ++kt) {
        const int k0 = kt * 64;
        const int cur = kt & 1;
        const bool more = (kt + 1 < nkt);
        if (more) {                           // issue next-tile loads (in flight)
            const ushort_t* kg = kbase + (size_t)(k0 + 64 + srow) * 64 + scol;
            const ushort_t* vg = vbase + (size_t)srow * 2048 + k0 + 64 + scol;
            kv0 = *(const short8*)(kg);
            vv0 = *(const short8*)(vg);
        }

        if (k0 <= row_max) {
            const ushort_t* Kc = Ks[cur];
            const ushort_t* Vc = Vs[cur];
            const bool diag = (k0 + 63 > base);   // wave-uniform

            // Per 16-key chunk: S^T = K Q^T, mask, exp2, pack -> pks.
            uint2_t pks[4];
            float ps0 = 0.f;
#pragma unroll
            for (int t4 = 0; t4 < 4; ++t4) {
                const short8 kf0 = *(const short8*)&Kc[(t4*16 + qr)*LDK + quad*8];
                const short8 kf1 = *(const short8*)&Kc[(t4*16 + qr)*LDK + 32 + quad*8];
                f32x4 a = (f32x4){0.f,0.f,0.f,0.f};
                a = __builtin_amdgcn_mfma_f32_16x16x32_bf16(kf0, Qb00, a, 0,0,0);
                a = __builtin_amdgcn_mfma_f32_16x16x32_bf16(kf1, Qb01, a, 0,0,0);
                if (diag) {
#pragma unroll
                    for (int r = 0; r < 4; ++r) {
                        const int key = k0 + t4*16 + quad*4 + r;
                        if (key > qv0) a[r] = -INFINITY;
                    }
                }
                float p0[4];
#pragma unroll
                for (int r = 0; r < 4; ++r) {
                    p0[r] = exp2f(__builtin_fmaf(a[r], SCL, -CB));
                    ps0 += p0[r];
                }
                pks[t4][0] = pk2bf(p0[0], p0[1]);
                pks[t4][1] = pk2bf(p0[2], p0[3]);
            }
            l_s += ps0;

            // O += P V : B-frag = V[key][d] from Vs[d][t], k=quad*4..+3
            __builtin_amdgcn_s_setprio(1);
#pragma unroll
            for (int dt = 0; dt < 4; ++dt) {
#pragma unroll
                for (int t4 = 0; t4 < 4; ++t4) {
                    const uint2_t vf = *(const uint2_t*)
                        &Vc[(dt*16 + qr)*LDK + t4*16 + quad*4];
                    Oacc[dt] = mfma16(pks[t4], vf, Oacc[dt]);
                }
            }
            __builtin_amdgcn_s_setprio(0);
        }

        if (more) {                           // stage tile kt+1 into other buf
            *(short8*)&Ks[cur ^ 1][srow * LDK + scol] = kv0;
            *(short8*)&Vs[cur ^ 1][srow * LDK + scol] = vv0;
        }
        __syncthreads();                      // buf ready / reads of cur done
    }

    // epilogue: reduce l across quads, store
    float lf = l_s;
    lf += __shfl_xor(lf, 16);
    lf += __shfl_xor(lf, 32);
#pragma unroll
    for (int r = 0; r < 4; ++r) {
        const float lr  = __shfl(lf, quad*4 + r);
        const float inv = 1.f / lr;
        const int q = q0 + wv*16 + quad*4 + r;
        float* o = out + ((size_t)(b*2048 + q)) * 1024 + h*64;
#pragma unroll
        for (int dt = 0; dt < 4; ++dt) o[dt*16 + qr] = Oacc[dt][r] * inv;
    }
}

extern "C" void kernel_launch(void* const* d_in, const int* in_sizes, int n_in,
                              void* d_out, int out_size, void* d_ws, size_t ws_size,
                              hipStream_t stream) {
    (void)in_sizes; (void)n_in; (void)out_size; (void)ws_size;
    const float* x  = (const float*)d_in[0];
    const float* w  = (const float*)d_in[1];
    const float* bq = (const float*)d_in[2];
    float* out = (float*)d_out;

    ushort_t* kws = (ushort_t*)d_ws;
    ushort_t* qws = kws + (size_t)8388608;
    ushort_t* vws = qws + (size_t)8388608;
    ushort_t* xb  = vws + (size_t)8388608;
    ushort_t* wt  = xb  + (size_t)8388608;

    cvt_xw<<<5632, 256, 0, stream>>>(x, xb, w, wt);
    qkv_gemm<<<dim3(64, 24), 256, 0, stream>>>(xb, wt, bq, kws, qws, vws);
    attn_fwd<<<1024, 512, 0, stream>>>(kws, qws, vws, out);
}